// Round 7
// baseline (198.987 us; speedup 1.0000x reference)
//
#include <hip/hip_runtime.h>
#include <math.h>

// ---------------------------------------------------------------------------
// TransformerEncoderLayer (prenorm), T=2048, N=4, H=512.
// SCALE = 1/(512^64) underflows to 0.0f => softmax uniform => attention out =
// per-batch mean of V rows (round-0 derivation; validated).
// Round 6 (fourth resubmit; rounds 3-6 hit GPU-acquisition timeouts):
// hi-only bf16 weights (1 MFMA per frag pair), fragment-ordered operands in
// global memory (conflict-free ds_read_b128 + linear global_load_lds), BK=64.
//
// Fragment order for matrix X[R][K] (bf16): tile = 16 rows x 32 k.
//   halfword idx = ((rt*KT + kt)*512) + c*8 + kin
//   rt=row>>4, kt=k>>5, c = ((k>>3)&3)*16 + (row&15), kin = k&7, KT = K/32.
// A wave's ds_read_b128 at lane*16B within a tile gives lane l:
//   row = l&15, k-chunk = l>>4  == the mfma_f32_16x16x32_bf16 operand map.
// ---------------------------------------------------------------------------

#define DEVI __device__ __forceinline__

typedef unsigned short u16;
typedef unsigned int   u32;
using short8 = __attribute__((ext_vector_type(8))) short;
using f32x4  = __attribute__((ext_vector_type(4))) float;

constexpr int T_ = 2048;
constexpr int NB = 4;
constexpr int H  = 512;
constexpr int M  = T_ * NB;      // 8192 rows
constexpr int FF = 2 * H;        // 1024
constexpr float LN_EPS = 1e-5f;
constexpr int NCHUNK = 256;

DEVI u16 f2bf(float f) {
    union { float f; u32 u; } v; v.f = f;
    u32 r = v.u + 0x7FFFu + ((v.u >> 16) & 1u);   // RNE
    return (u16)(r >> 16);
}

DEVI void gload16(const u16* src, u16* lds) {
    __builtin_amdgcn_global_load_lds(
        (const __attribute__((address_space(1))) u32*)src,
        (__attribute__((address_space(3))) u32*)lds, 16, 0, 0);
}

DEVI float hsum8(const float4& a, const float4& b) {
    return a.x + a.y + a.z + a.w + b.x + b.y + b.z + b.w;
}
DEVI float hsq8(const float4& a, const float4& b) {
    return a.x*a.x + a.y*a.y + a.z*a.z + a.w*a.w +
           b.x*b.x + b.y*b.y + b.z*b.z + b.w*b.w;
}
DEVI float4 ln_apply(const float4& v, float mean, float rs,
                     const float4& g, const float4& b) {
    float4 r;
    r.x = (v.x - mean) * rs * g.x + b.x;
    r.y = (v.y - mean) * rs * g.y + b.y;
    r.z = (v.z - mean) * rs * g.z + b.z;
    r.w = (v.w - mean) * rs * g.w + b.w;
    return r;
}
DEVI void add4(float4& a, const float4& b) {
    a.x += b.x; a.y += b.y; a.z += b.z; a.w += b.w;
}
DEVI void wave_reduce2(float& s, float& q) {
    #pragma unroll
    for (int m = 1; m < 64; m <<= 1) {
        s += __shfl_xor(s, m, 64);
        q += __shfl_xor(q, m, 64);
    }
}

// ---------------------------------------------------------------------------
// K1: per-row LN1 + per-batch partial sums over t. 256 blocks x 4 waves.
// ---------------------------------------------------------------------------
__global__ __launch_bounds__(256) void k_ln1_partial(
    const float* __restrict__ x, const float* __restrict__ g,
    const float* __restrict__ be, float* __restrict__ partials)
{
    const int lane = threadIdx.x & 63;
    const int w    = threadIdx.x >> 6;   // wave id == batch id
    const int t0   = blockIdx.x * 8;

    const float4* G4 = (const float4*)g;
    const float4* B4 = (const float4*)be;
    const float4 g0 = G4[lane], g1 = G4[64 + lane];
    const float4 b0 = B4[lane], b1 = B4[64 + lane];

    float4 acc0 = {0, 0, 0, 0}, acc1 = {0, 0, 0, 0};
    for (int i = 0; i < 8; ++i) {
        const int r = (t0 + i) * NB + w;
        const float4* X4 = (const float4*)(x + (size_t)r * H);
        float4 v0 = X4[lane], v1 = X4[64 + lane];
        float s = hsum8(v0, v1);
        float q = hsq8(v0, v1);
        wave_reduce2(s, q);
        const float mean = s * (1.0f / H);
        const float var  = q * (1.0f / H) - mean * mean;
        const float rs   = 1.0f / sqrtf(var + LN_EPS);
        add4(acc0, ln_apply(v0, mean, rs, g0, b0));
        add4(acc1, ln_apply(v1, mean, rs, g1, b1));
    }
    float4* P4 = (float4*)(partials + ((size_t)w * NCHUNK + blockIdx.x) * H);
    P4[lane]      = acc0;
    P4[64 + lane] = acc1;
}

// ---------------------------------------------------------------------------
// K2: reduce partials -> mean_h1[b][e]. 64 blocks x 256; 8 threads/output.
// ---------------------------------------------------------------------------
__global__ __launch_bounds__(256) void k_reduce_mean(
    const float* __restrict__ partials, float* __restrict__ mean_h1)
{
    const int tid = blockIdx.x * 256 + threadIdx.x;
    const int out = tid >> 3;            // 0..2047
    const int sub = tid & 7;
    const int b = out >> 9;
    const int e = out & 511;
    float s = 0.f;
    #pragma unroll 8
    for (int i = 0; i < 32; ++i) {
        const int c = sub * 32 + i;
        s += partials[((size_t)b * NCHUNK + c) * H + e];
    }
    s += __shfl_xor(s, 1, 64);
    s += __shfl_xor(s, 2, 64);
    s += __shfl_xor(s, 4, 64);
    if (sub == 0) mean_h1[out] = s * (1.0f / T_);
}

// ---------------------------------------------------------------------------
// Thread-per-output GEMV with vec in LDS. grid = NB*2 blocks x 256 thr.
// out[b][j] = bias[j] + dot(vec[b,:], W[:, colofs+j])
// ---------------------------------------------------------------------------
__global__ __launch_bounds__(256) void k_gemv_tpo(
    const float* __restrict__ vec, const float* __restrict__ W,
    const float* __restrict__ bias, float* __restrict__ outv,
    const int Kd, const int rowstride, const int colofs)
{
    __shared__ float v[512];
    const int t = threadIdx.x;
    const int b = blockIdx.x >> 1;
    const int j = (blockIdx.x & 1) * 256 + t;
    for (int i = t; i < Kd; i += 256) v[i] = vec[(size_t)b * Kd + i];
    __syncthreads();
    float acc = bias[j];
    const float* wp = W + colofs + j;
    #pragma unroll 8
    for (int k = 0; k < Kd; ++k)
        acc = fmaf(v[k], wp[(size_t)k * rowstride], acc);
    outv[(size_t)b * 512 + j] = acc;
}

// ---------------------------------------------------------------------------
// K5: h2 = LN2(x + c[b]) -> bf16 in FRAGMENT ORDER (h2': [512 mt][16 kt][512])
// one wave per row; lane covers k = lane*8 .. +7.
// ---------------------------------------------------------------------------
__global__ __launch_bounds__(256) void k_ln2(
    const float* __restrict__ x, const float* __restrict__ cvec,
    const float* __restrict__ g, const float* __restrict__ be,
    u16* __restrict__ h2f)
{
    const int lane = threadIdx.x & 63;
    const int w    = threadIdx.x >> 6;
    const int r    = blockIdx.x * 4 + w;
    const int b    = r & 3;

    const float4* X4 = (const float4*)(x + (size_t)r * H);
    const float4* C4 = (const float4*)(cvec + (size_t)b * H);
    float4 v0 = X4[lane * 2],     v1 = X4[lane * 2 + 1];
    add4(v0, C4[lane * 2]);
    add4(v1, C4[lane * 2 + 1]);

    float s = hsum8(v0, v1);
    float q = hsq8(v0, v1);
    wave_reduce2(s, q);
    const float mean = s * (1.0f / H);
    const float var  = q * (1.0f / H) - mean * mean;
    const float rs   = 1.0f / sqrtf(var + LN_EPS);

    const float4* G4 = (const float4*)g;
    const float4* B4 = (const float4*)be;
    float4 h0 = ln_apply(v0, mean, rs, G4[lane * 2],     B4[lane * 2]);
    float4 h1 = ln_apply(v1, mean, rs, G4[lane * 2 + 1], B4[lane * 2 + 1]);

    short8 o;
    o[0] = f2bf(h0.x); o[1] = f2bf(h0.y); o[2] = f2bf(h0.z); o[3] = f2bf(h0.w);
    o[4] = f2bf(h1.x); o[5] = f2bf(h1.y); o[6] = f2bf(h1.z); o[7] = f2bf(h1.w);

    // dest: rt=r>>4, kt=lane>>2, c=(lane&3)*16 + (r&15), kin 0..7
    const size_t idx = (((size_t)(r >> 4) * 16 + (lane >> 2)) << 9)
                     + ((lane & 3) * 16 + (r & 15)) * 8;
    *(short8*)&h2f[idx] = o;
}

// ---------------------------------------------------------------------------
// Weight transpose -> bf16(hi) in fragment order. W[K][N] -> W'[N/16][K/32][512]
// grid (K/32, N/32), 256 threads.
// ---------------------------------------------------------------------------
__global__ __launch_bounds__(256) void k_wsplit(
    const float* __restrict__ W, u16* __restrict__ Wf,
    const int K, const int N)
{
    __shared__ float tile[32][33];
    const int k0 = blockIdx.x * 32, n0 = blockIdx.y * 32;
    const int t = threadIdx.x;
    const int KT = K >> 5;
    #pragma unroll
    for (int i = 0; i < 4; ++i) {
        const int idx = t + i * 256;
        const int r = idx >> 5, c = idx & 31;
        tile[r][c] = W[(size_t)(k0 + r) * N + n0 + c];
    }
    __syncthreads();
    if (t < 128) {
        const int tt = t >> 6;         // n-subtile 0..1
        const int c  = t & 63;         // chunk: row=(c&15), k8=(c>>4)
        short8 o;
        #pragma unroll
        for (int kin = 0; kin < 8; ++kin)
            o[kin] = f2bf(tile[(c >> 4) * 8 + kin][tt * 16 + (c & 15)]);
        const size_t idx = (((size_t)(n0 / 16 + tt) * KT + (k0 >> 5)) << 9)
                         + c * 8;
        *(short8*)&Wf[idx] = o;
    }
}

// ---------------------------------------------------------------------------
// bf16 MFMA GEMM on fragment-ordered operands. BK=64, 256 thr = 4 waves (2x2).
// A' [M/16][K/32][512], B' [N/16][K/32][512].
// MODE 0: out -> fragment-ordered bf16 (outfrag), with relu(.+bias)
// MODE 1: out -> row-major fp32 (outf) = .+bias+resid_x+resid_c[row&3], N=512
// ---------------------------------------------------------------------------
template<int MODE>
__global__ __launch_bounds__(256) void gemm_bf16(
    const u16* __restrict__ Af, const u16* __restrict__ Bf,
    const float* __restrict__ bias,
    const float* __restrict__ resid_x, const float* __restrict__ resid_c,
    float* __restrict__ outf, u16* __restrict__ outfrag,
    const int K, const int N)
{
    constexpr int BM = 128, BN = 128, BK = 64;
    const int KT = K >> 5;                 // global k-tiles
    __shared__ alignas(16) u16 As[BM * BK];   // [mt 0..7][ktl 0..1][512]
    __shared__ alignas(16) u16 Bs[BN * BK];

    const int t    = threadIdx.x;
    const int lane = t & 63, w = t >> 6;
    const int wr = w >> 1, wc = w & 1;
    const int lr = lane & 15, lk = lane >> 4;
    const int bmt = blockIdx.x * 8;        // block's first m-tile
    const int bnt = blockIdx.y * 8;        // block's first n-tile

    f32x4 acc[4][4];
    #pragma unroll
    for (int i = 0; i < 4; ++i)
        #pragma unroll
        for (int j = 0; j < 4; ++j)
            acc[i][j] = (f32x4){0.f, 0.f, 0.f, 0.f};

    for (int kt0 = 0; kt0 < KT; kt0 += 2) {
        __syncthreads();
        #pragma unroll
        for (int ft = 0; ft < 4; ++ft) {
            const int f = ft * 256 + t;
            const int mt = f >> 7, ktl = (f >> 6) & 1, c = f & 63;
            gload16(Af + (((size_t)(bmt + mt) * KT + kt0 + ktl) << 9) + c * 8,
                    &As[f * 8]);
        }
        #pragma unroll
        for (int ft = 0; ft < 4; ++ft) {
            const int f = ft * 256 + t;
            const int nt = f >> 7, ktl = (f >> 6) & 1, c = f & 63;
            gload16(Bf + (((size_t)(bnt + nt) * KT + kt0 + ktl) << 9) + c * 8,
                    &Bs[f * 8]);
        }
        __syncthreads();

        #pragma unroll
        for (int ktl = 0; ktl < 2; ++ktl) {
            short8 a[4], b[4];
            #pragma unroll
            for (int i = 0; i < 4; ++i)
                a[i] = *(const short8*)&As[(((wr * 4 + i) * 2 + ktl) << 9) + lane * 8];
            #pragma unroll
            for (int j = 0; j < 4; ++j)
                b[j] = *(const short8*)&Bs[(((wc * 4 + j) * 2 + ktl) << 9) + lane * 8];
            #pragma unroll
            for (int i = 0; i < 4; ++i)
                #pragma unroll
                for (int j = 0; j < 4; ++j)
                    acc[i][j] = __builtin_amdgcn_mfma_f32_16x16x32_bf16(
                        a[i], b[j], acc[i][j], 0, 0, 0);
        }
    }

    // epilogue: D col = lane&15, row = (lane>>4)*4 + reg   [m89/m91]
    const int K2T = N >> 5;   // out-as-A' k-tiles (MODE 0)
    #pragma unroll
    for (int i = 0; i < 4; ++i) {
        const int rt   = bmt + wr * 4 + i;
        const int row0 = rt * 16 + lk * 4;
        #pragma unroll
        for (int j = 0; j < 4; ++j) {
            const int col = (bnt + wc * 4 + j) * 16 + lr;
            const float bv = bias[col];
            #pragma unroll
            for (int r = 0; r < 4; ++r) {
                const int row = row0 + r;
                float v = acc[i][j][r] + bv;
                if (MODE == 0) {
                    v = fmaxf(v, 0.f);
                    const size_t idx =
                        (((size_t)rt * K2T + (col >> 5)) << 9)
                        + (((col >> 3) & 3) * 16 + (lk * 4 + r)) * 8
                        + (col & 7);
                    outfrag[idx] = f2bf(v);
                } else {
                    v += resid_x[(size_t)row * N + col]
                       + resid_c[(row & 3) * N + col];
                    outf[(size_t)row * N + col] = v;
                }
            }
        }
    }
}

// ---------------------------------------------------------------------------
extern "C" void kernel_launch(void* const* d_in, const int* in_sizes, int n_in,
                              void* d_out, int out_size, void* d_ws, size_t ws_size,
                              hipStream_t stream)
{
    const float* x     = (const float*)d_in[0];
    const float* qkv_w = (const float*)d_in[1];
    const float* qkv_b = (const float*)d_in[2];
    const float* out_w = (const float*)d_in[3];
    const float* out_b = (const float*)d_in[4];
    const float* ln1_g = (const float*)d_in[5];
    const float* ln1_b = (const float*)d_in[6];
    const float* ff1_w = (const float*)d_in[7];
    const float* ff1_b = (const float*)d_in[8];
    const float* ff2_w = (const float*)d_in[9];
    const float* ff2_b = (const float*)d_in[10];
    const float* ln2_g = (const float*)d_in[11];
    const float* ln2_b = (const float*)d_in[12];

    float* out = (float*)d_out;

    float* fws      = (float*)d_ws;
    float* partials = fws;                                   // 4*256*512
    float* mh       = fws + (size_t)4 * NCHUNK * H;          // 2048
    float* vmean    = mh + NB * H;                           // 2048
    float* cvec     = vmean + NB * H;                        // 2048
    u16*   h2f      = (u16*)(cvec + NB * H);                 // M*H    (frag)
    u16*   f1f      = h2f + (size_t)M * H;                   // M*FF   (frag)
    u16*   w1f      = f1f + (size_t)M * FF;                  // FF x H (frag)
    u16*   w2f      = w1f + (size_t)H * FF;                  // H x FF (frag)

    // weight transpose+cast into fragment order (activation-independent)
    k_wsplit<<<dim3(H / 32, FF / 32), 256, 0, stream>>>(ff1_w, w1f, H, FF);
    k_wsplit<<<dim3(FF / 32, H / 32), 256, 0, stream>>>(ff2_w, w2f, FF, H);

    // attention path (collapsed: SCALE == 0 -> uniform softmax -> mean of V)
    k_ln1_partial<<<NCHUNK, 256, 0, stream>>>(x, ln1_g, ln1_b, partials);
    k_reduce_mean<<<64, 256, 0, stream>>>(partials, mh);
    k_gemv_tpo<<<8, 256, 0, stream>>>(mh, qkv_w, qkv_b + 2 * H, vmean,
                                      H, 3 * H, 2 * H);      // Wv slice
    k_gemv_tpo<<<8, 256, 0, stream>>>(vmean, out_w, out_b, cvec,
                                      H, H, 0);

    // h2' = LN2(x + c) in fragment order
    k_ln2<<<M / 4, 256, 0, stream>>>(x, cvec, ln2_g, ln2_b, h2f);

    // f1' = frag(bf16(relu(h2' @ ff1_w + b1)))   [8192,512]@[512,1024]
    gemm_bf16<0><<<dim3(M / 128, FF / 128), 256, 0, stream>>>(
        h2f, w1f, ff1_b, nullptr, nullptr, nullptr, f1f, H, FF);

    // out = x + c + f1' @ ff2_w + b2             [8192,1024]@[1024,512]
    gemm_bf16<1><<<dim3(M / 128, H / 128), 256, 0, stream>>>(
        f1f, w2f, ff2_b, x, cvec, out, nullptr, FF, H);
}

// Round 10
// 176.857 us; speedup vs baseline: 1.1251x; 1.1251x over previous
//
#include <hip/hip_runtime.h>
#include <math.h>

// ---------------------------------------------------------------------------
// TransformerEncoderLayer (prenorm), T=2048, N=4, H=512.
// SCALE = 1/(512^64) underflows to 0.0f => softmax uniform => attention out =
// per-batch mean of V rows (round-0 derivation; validated r2/r7).
// Round 9 resubmit (rounds 8-9 hit GPU-acquisition timeouts): serial-chain
// attack. 9 -> 7 dispatches (merged weight-prep kernel, reduce_mean folded
// into LN1 via fp32 atomics), GEMVs at wide parallelism with coalesced
// weight reads. GEMM/LN2/fragment layout byte-identical to validated r7.
//
// Fragment order for matrix X[R][K] (bf16): tile = 16 rows x 32 k.
//   halfword idx = ((rt*KT + kt)*512) + c*8 + kin
//   rt=row>>4, kt=k>>5, c = ((k>>3)&3)*16 + (row&15), kin = k&7, KT = K/32.
// ---------------------------------------------------------------------------

#define DEVI __device__ __forceinline__

typedef unsigned short u16;
typedef unsigned int   u32;
using short8 = __attribute__((ext_vector_type(8))) short;
using f32x4  = __attribute__((ext_vector_type(4))) float;

constexpr int T_ = 2048;
constexpr int NB = 4;
constexpr int H  = 512;
constexpr int M  = T_ * NB;      // 8192 rows
constexpr int FF = 2 * H;        // 1024
constexpr float LN_EPS = 1e-5f;

DEVI u16 f2bf(float f) {
    union { float f; u32 u; } v; v.f = f;
    u32 r = v.u + 0x7FFFu + ((v.u >> 16) & 1u);   // RNE
    return (u16)(r >> 16);
}

DEVI void gload16(const u16* src, u16* lds) {
    __builtin_amdgcn_global_load_lds(
        (const __attribute__((address_space(1))) u32*)src,
        (__attribute__((address_space(3))) u32*)lds, 16, 0, 0);
}

DEVI float hsum8(const float4& a, const float4& b) {
    return a.x + a.y + a.z + a.w + b.x + b.y + b.z + b.w;
}
DEVI float hsq8(const float4& a, const float4& b) {
    return a.x*a.x + a.y*a.y + a.z*a.z + a.w*a.w +
           b.x*b.x + b.y*b.y + b.z*b.z + b.w*b.w;
}
DEVI float4 ln_apply(const float4& v, float mean, float rs,
                     const float4& g, const float4& b) {
    float4 r;
    r.x = (v.x - mean) * rs * g.x + b.x;
    r.y = (v.y - mean) * rs * g.y + b.y;
    r.z = (v.z - mean) * rs * g.z + b.z;
    r.w = (v.w - mean) * rs * g.w + b.w;
    return r;
}
DEVI void add4(float4& a, const float4& b) {
    a.x += b.x; a.y += b.y; a.z += b.z; a.w += b.w;
}
DEVI void wave_reduce2(float& s, float& q) {
    #pragma unroll
    for (int m = 1; m < 64; m <<= 1) {
        s += __shfl_xor(s, m, 64);
        q += __shfl_xor(q, m, 64);
    }
}

// ---------------------------------------------------------------------------
// K0 "prep": both weight transposes -> bf16(hi) fragment order, + zero mh.
// 1024 blocks: [0,512) = ff1_w (K=512,N=1024), [512,1024) = ff2_w (K=1024,N=512).
// Runs before k_ln1 in stream order, so mh is zeroed before atomics begin.
// ---------------------------------------------------------------------------
__global__ __launch_bounds__(256) void k_prep(
    const float* __restrict__ W1, const float* __restrict__ W2,
    u16* __restrict__ w1f, u16* __restrict__ w2f, float* __restrict__ mh)
{
    __shared__ float tile[32][33];
    const int t = threadIdx.x;
    const int bid = blockIdx.x;

    if (bid == 0) {
        for (int i = t; i < NB * H; i += 256) mh[i] = 0.f;
    }

    const float* W;
    u16* Wf;
    int K, N, k0, n0;
    if (bid < 512) {
        W = W1; Wf = w1f; K = H; N = FF;
        k0 = (bid & 15) * 32;  n0 = (bid >> 4) * 32;
    } else {
        const int b2 = bid - 512;
        W = W2; Wf = w2f; K = FF; N = H;
        k0 = (b2 & 31) * 32;   n0 = (b2 >> 5) * 32;
    }

    #pragma unroll
    for (int i = 0; i < 4; ++i) {
        const int idx = t + i * 256;
        const int r = idx >> 5, c = idx & 31;
        tile[r][c] = W[(size_t)(k0 + r) * N + n0 + c];
    }
    __syncthreads();
    if (t < 128) {
        const int tt = t >> 6;         // n-subtile 0..1
        const int c  = t & 63;         // chunk: row=(c&15), k8=(c>>4)
        short8 o;
        #pragma unroll
        for (int kin = 0; kin < 8; ++kin)
            o[kin] = f2bf(tile[(c >> 4) * 8 + kin][tt * 16 + (c & 15)]);
        const size_t idx = (((size_t)(n0 / 16 + tt) * (K >> 5) + (k0 >> 5)) << 9)
                         + c * 8;
        *(short8*)&Wf[idx] = o;
    }
}

// ---------------------------------------------------------------------------
// K1: per-row LN1, per-batch sums accumulated straight into mh via atomics.
// 256 blocks x 4 waves; wave w = batch w, 8 t's per block.
// ---------------------------------------------------------------------------
__global__ __launch_bounds__(256) void k_ln1_atomic(
    const float* __restrict__ x, const float* __restrict__ g,
    const float* __restrict__ be, float* __restrict__ mh)
{
    const int lane = threadIdx.x & 63;
    const int w    = threadIdx.x >> 6;   // wave id == batch id
    const int t0   = blockIdx.x * 8;

    const float4* G4 = (const float4*)g;
    const float4* B4 = (const float4*)be;
    const float4 g0 = G4[lane], g1 = G4[64 + lane];
    const float4 b0 = B4[lane], b1 = B4[64 + lane];

    float4 acc0 = {0, 0, 0, 0}, acc1 = {0, 0, 0, 0};
    for (int i = 0; i < 8; ++i) {
        const int r = (t0 + i) * NB + w;
        const float4* X4 = (const float4*)(x + (size_t)r * H);
        float4 v0 = X4[lane], v1 = X4[64 + lane];
        float s = hsum8(v0, v1);
        float q = hsq8(v0, v1);
        wave_reduce2(s, q);
        const float mean = s * (1.0f / H);
        const float var  = q * (1.0f / H) - mean * mean;
        const float rs   = 1.0f / sqrtf(var + LN_EPS);
        add4(acc0, ln_apply(v0, mean, rs, g0, b0));
        add4(acc1, ln_apply(v1, mean, rs, g1, b1));
    }
    float* dst = mh + (size_t)w * H;
    atomicAdd(&dst[lane * 4 + 0],       acc0.x);
    atomicAdd(&dst[lane * 4 + 1],       acc0.y);
    atomicAdd(&dst[lane * 4 + 2],       acc0.z);
    atomicAdd(&dst[lane * 4 + 3],       acc0.w);
    atomicAdd(&dst[256 + lane * 4 + 0], acc1.x);
    atomicAdd(&dst[256 + lane * 4 + 1], acc1.y);
    atomicAdd(&dst[256 + lane * 4 + 2], acc1.z);
    atomicAdd(&dst[256 + lane * 4 + 3], acc1.w);
}

// ---------------------------------------------------------------------------
// Coalesced GEMV: out[b][j] = bias[j] + sum_k (vec[b][k]*vscale) * W[k][colofs+j]
// 128 blocks x 256 thr. Block = (b = bid>>5, 16-wide j chunk = bid&31).
// Thread: jj = t&15 (j within chunk), ks = t>>4 (one of 16 k-slices of 32).
// 16 consecutive lanes read 16 consecutive floats -> 64B coalesced per step.
// ---------------------------------------------------------------------------
__global__ __launch_bounds__(256) void k_gemv_coal(
    const float* __restrict__ vec, const float* __restrict__ W,
    const float* __restrict__ bias, float* __restrict__ outv,
    const int Kd, const int stride, const int colofs, const float vscale)
{
    __shared__ float red[16][17];
    const int t  = threadIdx.x;
    const int b  = blockIdx.x >> 5;
    const int j0 = (blockIdx.x & 31) * 16;
    const int jj = t & 15, ks = t >> 4;

    const float* vp = vec + (size_t)b * Kd + ks * 32;
    const float* wp = W + (size_t)(ks * 32) * stride + colofs + j0 + jj;
    float acc = 0.f;
    #pragma unroll 8
    for (int i = 0; i < 32; ++i)
        acc = fmaf(vp[i] * vscale, wp[(size_t)i * stride], acc);

    red[ks][jj] = acc;
    __syncthreads();
    if (t < 16) {
        float s = 0.f;
        #pragma unroll
        for (int k2 = 0; k2 < 16; ++k2) s += red[k2][t];
        outv[(size_t)b * 512 + j0 + t] = s + bias[j0 + t];
    }
}

// ---------------------------------------------------------------------------
// K5: h2 = LN2(x + c[b]) -> bf16 in FRAGMENT ORDER (h2': [512 mt][16 kt][512])
// one wave per row; lane covers k = lane*8 .. +7.   (unchanged, validated)
// ---------------------------------------------------------------------------
__global__ __launch_bounds__(256) void k_ln2(
    const float* __restrict__ x, const float* __restrict__ cvec,
    const float* __restrict__ g, const float* __restrict__ be,
    u16* __restrict__ h2f)
{
    const int lane = threadIdx.x & 63;
    const int w    = threadIdx.x >> 6;
    const int r    = blockIdx.x * 4 + w;
    const int b    = r & 3;

    const float4* X4 = (const float4*)(x + (size_t)r * H);
    const float4* C4 = (const float4*)(cvec + (size_t)b * H);
    float4 v0 = X4[lane * 2],     v1 = X4[lane * 2 + 1];
    add4(v0, C4[lane * 2]);
    add4(v1, C4[lane * 2 + 1]);

    float s = hsum8(v0, v1);
    float q = hsq8(v0, v1);
    wave_reduce2(s, q);
    const float mean = s * (1.0f / H);
    const float var  = q * (1.0f / H) - mean * mean;
    const float rs   = 1.0f / sqrtf(var + LN_EPS);

    const float4* G4 = (const float4*)g;
    const float4* B4 = (const float4*)be;
    float4 h0 = ln_apply(v0, mean, rs, G4[lane * 2],     B4[lane * 2]);
    float4 h1 = ln_apply(v1, mean, rs, G4[lane * 2 + 1], B4[lane * 2 + 1]);

    short8 o;
    o[0] = f2bf(h0.x); o[1] = f2bf(h0.y); o[2] = f2bf(h0.z); o[3] = f2bf(h0.w);
    o[4] = f2bf(h1.x); o[5] = f2bf(h1.y); o[6] = f2bf(h1.z); o[7] = f2bf(h1.w);

    // dest: rt=r>>4, kt=lane>>2, c=(lane&3)*16 + (r&15), kin 0..7
    const size_t idx = (((size_t)(r >> 4) * 16 + (lane >> 2)) << 9)
                     + ((lane & 3) * 16 + (r & 15)) * 8;
    *(short8*)&h2f[idx] = o;
}

// ---------------------------------------------------------------------------
// bf16 MFMA GEMM on fragment-ordered operands. BK=64, 256 thr = 4 waves (2x2).
// A' [M/16][K/32][512], B' [N/16][K/32][512].      (unchanged, validated)
// MODE 0: out -> fragment-ordered bf16 (outfrag), with relu(.+bias)
// MODE 1: out -> row-major fp32 (outf) = .+bias+resid_x+resid_c[row&3], N=512
// ---------------------------------------------------------------------------
template<int MODE>
__global__ __launch_bounds__(256) void gemm_bf16(
    const u16* __restrict__ Af, const u16* __restrict__ Bf,
    const float* __restrict__ bias,
    const float* __restrict__ resid_x, const float* __restrict__ resid_c,
    float* __restrict__ outf, u16* __restrict__ outfrag,
    const int K, const int N)
{
    constexpr int BM = 128, BN = 128, BK = 64;
    const int KT = K >> 5;                 // global k-tiles
    __shared__ alignas(16) u16 As[BM * BK];   // [mt 0..7][ktl 0..1][512]
    __shared__ alignas(16) u16 Bs[BN * BK];

    const int t    = threadIdx.x;
    const int lane = t & 63, w = t >> 6;
    const int wr = w >> 1, wc = w & 1;
    const int lr = lane & 15, lk = lane >> 4;
    const int bmt = blockIdx.x * 8;        // block's first m-tile
    const int bnt = blockIdx.y * 8;        // block's first n-tile

    f32x4 acc[4][4];
    #pragma unroll
    for (int i = 0; i < 4; ++i)
        #pragma unroll
        for (int j = 0; j < 4; ++j)
            acc[i][j] = (f32x4){0.f, 0.f, 0.f, 0.f};

    for (int kt0 = 0; kt0 < KT; kt0 += 2) {
        __syncthreads();
        #pragma unroll
        for (int ft = 0; ft < 4; ++ft) {
            const int f = ft * 256 + t;
            const int mt = f >> 7, ktl = (f >> 6) & 1, c = f & 63;
            gload16(Af + (((size_t)(bmt + mt) * KT + kt0 + ktl) << 9) + c * 8,
                    &As[f * 8]);
        }
        #pragma unroll
        for (int ft = 0; ft < 4; ++ft) {
            const int f = ft * 256 + t;
            const int nt = f >> 7, ktl = (f >> 6) & 1, c = f & 63;
            gload16(Bf + (((size_t)(bnt + nt) * KT + kt0 + ktl) << 9) + c * 8,
                    &Bs[f * 8]);
        }
        __syncthreads();

        #pragma unroll
        for (int ktl = 0; ktl < 2; ++ktl) {
            short8 a[4], b[4];
            #pragma unroll
            for (int i = 0; i < 4; ++i)
                a[i] = *(const short8*)&As[(((wr * 4 + i) * 2 + ktl) << 9) + lane * 8];
            #pragma unroll
            for (int j = 0; j < 4; ++j)
                b[j] = *(const short8*)&Bs[(((wc * 4 + j) * 2 + ktl) << 9) + lane * 8];
            #pragma unroll
            for (int i = 0; i < 4; ++i)
                #pragma unroll
                for (int j = 0; j < 4; ++j)
                    acc[i][j] = __builtin_amdgcn_mfma_f32_16x16x32_bf16(
                        a[i], b[j], acc[i][j], 0, 0, 0);
        }
    }

    // epilogue: D col = lane&15, row = (lane>>4)*4 + reg   [m89/m91]
    const int K2T = N >> 5;   // out-as-A' k-tiles (MODE 0)
    #pragma unroll
    for (int i = 0; i < 4; ++i) {
        const int rt   = bmt + wr * 4 + i;
        const int row0 = rt * 16 + lk * 4;
        #pragma unroll
        for (int j = 0; j < 4; ++j) {
            const int col = (bnt + wc * 4 + j) * 16 + lr;
            const float bv = bias[col];
            #pragma unroll
            for (int r = 0; r < 4; ++r) {
                const int row = row0 + r;
                float v = acc[i][j][r] + bv;
                if (MODE == 0) {
                    v = fmaxf(v, 0.f);
                    const size_t idx =
                        (((size_t)rt * K2T + (col >> 5)) << 9)
                        + (((col >> 3) & 3) * 16 + (lk * 4 + r)) * 8
                        + (col & 7);
                    outfrag[idx] = f2bf(v);
                } else {
                    v += resid_x[(size_t)row * N + col]
                       + resid_c[(row & 3) * N + col];
                    outf[(size_t)row * N + col] = v;
                }
            }
        }
    }
}

// ---------------------------------------------------------------------------
extern "C" void kernel_launch(void* const* d_in, const int* in_sizes, int n_in,
                              void* d_out, int out_size, void* d_ws, size_t ws_size,
                              hipStream_t stream)
{
    const float* x     = (const float*)d_in[0];
    const float* qkv_w = (const float*)d_in[1];
    const float* qkv_b = (const float*)d_in[2];
    const float* out_w = (const float*)d_in[3];
    const float* out_b = (const float*)d_in[4];
    const float* ln1_g = (const float*)d_in[5];
    const float* ln1_b = (const float*)d_in[6];
    const float* ff1_w = (const float*)d_in[7];
    const float* ff1_b = (const float*)d_in[8];
    const float* ff2_w = (const float*)d_in[9];
    const float* ff2_b = (const float*)d_in[10];
    const float* ln2_g = (const float*)d_in[11];
    const float* ln2_b = (const float*)d_in[12];

    float* out = (float*)d_out;

    float* fws   = (float*)d_ws;
    float* mh    = fws;                          // 2048 (zeroed by k_prep)
    float* vmean = mh + NB * H;                  // 2048
    float* cvec  = vmean + NB * H;               // 2048
    u16*   h2f   = (u16*)(cvec + NB * H);        // M*H    (frag)
    u16*   f1f   = h2f + (size_t)M * H;          // M*FF   (frag)
    u16*   w1f   = f1f + (size_t)M * FF;         // FF x H (frag)
    u16*   w2f   = w1f + (size_t)H * FF;         // H x FF (frag)

    // K0: weight transposes (both) + zero mh
    k_prep<<<1024, 256, 0, stream>>>(ff1_w, ff2_w, w1f, w2f, mh);

    // K1: LN1 + per-batch sum -> mh (atomics)
    k_ln1_atomic<<<256, 256, 0, stream>>>(x, ln1_g, ln1_b, mh);

    // K2/K3: vmean = (mh/T) @ Wv + bv ; cvec = vmean @ out_w + out_b
    k_gemv_coal<<<128, 256, 0, stream>>>(mh, qkv_w, qkv_b + 2 * H, vmean,
                                         H, 3 * H, 2 * H, 1.0f / T_);
    k_gemv_coal<<<128, 256, 0, stream>>>(vmean, out_w, out_b, cvec,
                                         H, H, 0, 1.0f);

    // K4: h2' = LN2(x + c) in fragment order
    k_ln2<<<M / 4, 256, 0, stream>>>(x, cvec, ln2_g, ln2_b, h2f);

    // K5: f1' = frag(bf16(relu(h2' @ ff1_w + b1)))   [8192,512]@[512,1024]
    gemm_bf16<0><<<dim3(M / 128, FF / 128), 256, 0, stream>>>(
        h2f, w1f, ff1_b, nullptr, nullptr, nullptr, f1f, H, FF);

    // K6: out = x + c + f1' @ ff2_w + b2             [8192,1024]@[1024,512]
    gemm_bf16<1><<<dim3(M / 128, H / 128), 256, 0, stream>>>(
        f1f, w2f, ff2_b, x, cvec, out, nullptr, FF, H);
}

// Round 13
// 170.325 us; speedup vs baseline: 1.1683x; 1.0383x over previous
//
#include <hip/hip_runtime.h>
#include <math.h>

// ---------------------------------------------------------------------------
// TransformerEncoderLayer (prenorm), T=2048, N=4, H=512.
// SCALE = 1/(512^64) underflows to 0.0f => softmax uniform => attention out =
// per-batch mean of V rows (round-0 derivation; validated r2/r7/r10).
// Round 13 resubmit (rounds 11-12 hit GPU-acquisition timeouts): launch-count
// attack, 7 -> 5 dispatches.
//   K0 mega-prep: wsplit(ff1)+wsplit(ff2)+Weff=Wv@Wout+beff+LN1->partials
//   K1 gemv_eff : cvec = (sum partials)/T @ Weff + beff
//   K2 ln2, K3 gemm1, K4 gemm2 : byte-identical validated code.
// Collapsing gemv1->gemv2 into Weff uses (mh@Wv)@Wout == mh@(Wv@Wout) (fp32,
// negligible reassociation error).
//
// Fragment order for matrix X[R][K] (bf16): tile = 16 rows x 32 k.
//   halfword idx = ((rt*KT + kt)*512) + c*8 + kin
//   rt=row>>4, kt=k>>5, c = ((k>>3)&3)*16 + (row&15), kin = k&7, KT = K/32.
// ---------------------------------------------------------------------------

#define DEVI __device__ __forceinline__

typedef unsigned short u16;
typedef unsigned int   u32;
using short8 = __attribute__((ext_vector_type(8))) short;
using f32x4  = __attribute__((ext_vector_type(4))) float;

constexpr int T_ = 2048;
constexpr int NB = 4;
constexpr int H  = 512;
constexpr int M  = T_ * NB;      // 8192 rows
constexpr int FF = 2 * H;        // 1024
constexpr float LN_EPS = 1e-5f;
constexpr int NCHUNK = 256;

DEVI u16 f2bf(float f) {
    union { float f; u32 u; } v; v.f = f;
    u32 r = v.u + 0x7FFFu + ((v.u >> 16) & 1u);   // RNE
    return (u16)(r >> 16);
}

DEVI void gload16(const u16* src, u16* lds) {
    __builtin_amdgcn_global_load_lds(
        (const __attribute__((address_space(1))) u32*)src,
        (__attribute__((address_space(3))) u32*)lds, 16, 0, 0);
}

DEVI float hsum8(const float4& a, const float4& b) {
    return a.x + a.y + a.z + a.w + b.x + b.y + b.z + b.w;
}
DEVI float hsq8(const float4& a, const float4& b) {
    return a.x*a.x + a.y*a.y + a.z*a.z + a.w*a.w +
           b.x*b.x + b.y*b.y + b.z*b.z + b.w*b.w;
}
DEVI float4 ln_apply(const float4& v, float mean, float rs,
                     const float4& g, const float4& b) {
    float4 r;
    r.x = (v.x - mean) * rs * g.x + b.x;
    r.y = (v.y - mean) * rs * g.y + b.y;
    r.z = (v.z - mean) * rs * g.z + b.z;
    r.w = (v.w - mean) * rs * g.w + b.w;
    return r;
}
DEVI void add4(float4& a, const float4& b) {
    a.x += b.x; a.y += b.y; a.z += b.z; a.w += b.w;
}
DEVI void wave_reduce2(float& s, float& q) {
    #pragma unroll
    for (int m = 1; m < 64; m <<= 1) {
        s += __shfl_xor(s, m, 64);
        q += __shfl_xor(q, m, 64);
    }
}

// block-range constants for the mega kernel
constexpr int NW1  = 512;                 // wsplit ff1
constexpr int NW2  = 512;                 // wsplit ff2
constexpr int NWE  = 256;                 // Weff 32x32 tiles (16x16)
constexpr int NBE  = 2;                   // beff (2 x 256 outputs)
constexpr int NLN  = 256;                 // ln1 partials
constexpr int MEGA_BLOCKS = NW1 + NW2 + NWE + NBE + NLN;   // 1538

// ---------------------------------------------------------------------------
// K0 mega-prep. All sections independent (weights-only or x-only).
// ---------------------------------------------------------------------------
__global__ __launch_bounds__(256) void k_mega(
    const float* __restrict__ W1, const float* __restrict__ W2,
    const float* __restrict__ qkv_w, const float* __restrict__ qkv_b,
    const float* __restrict__ out_w, const float* __restrict__ out_b,
    const float* __restrict__ x, const float* __restrict__ ln1g,
    const float* __restrict__ ln1b,
    u16* __restrict__ w1f, u16* __restrict__ w2f,
    float* __restrict__ Weff, float* __restrict__ beff,
    float* __restrict__ partials)
{
    __shared__ float smem[2 * 32 * 33];    // 8448 B
    const int t   = threadIdx.x;
    const int bid = blockIdx.x;

    if (bid < NW1 + NW2) {
        // ---- weight transpose -> bf16(hi) fragment order (validated) ----
        const float* W;
        u16* Wf;
        int K, N, k0, n0;
        if (bid < NW1) {
            W = W1; Wf = w1f; K = H; N = FF;
            k0 = (bid & 15) * 32;  n0 = (bid >> 4) * 32;
        } else {
            const int b2 = bid - NW1;
            W = W2; Wf = w2f; K = FF; N = H;
            k0 = (b2 & 31) * 32;   n0 = (b2 >> 5) * 32;
        }
        #pragma unroll
        for (int i = 0; i < 4; ++i) {
            const int idx = t + i * 256;
            const int r = idx >> 5, c = idx & 31;
            smem[r * 33 + c] = W[(size_t)(k0 + r) * N + n0 + c];
        }
        __syncthreads();
        if (t < 128) {
            const int tt = t >> 6;         // n-subtile 0..1
            const int c  = t & 63;         // chunk: row=(c&15), k8=(c>>4)
            short8 o;
            #pragma unroll
            for (int kin = 0; kin < 8; ++kin)
                o[kin] = f2bf(smem[((c >> 4) * 8 + kin) * 33 + tt * 16 + (c & 15)]);
            const size_t idx =
                (((size_t)(n0 / 16 + tt) * (K >> 5) + (k0 >> 5)) << 9) + c * 8;
            *(short8*)&Wf[idx] = o;
        }
    } else if (bid < NW1 + NW2 + NWE) {
        // ---- Weff[k][j] = sum_q Wv[k][q] * Wout[q][j], 32x32 tile ----
        const int b3 = bid - (NW1 + NW2);
        const int kt = b3 & 15, jt = b3 >> 4;
        float* Av = smem;                  // [32][33]
        float* Bo = smem + 32 * 33;        // [32][33]
        const int r  = t >> 3;             // 0..31
        const int c4 = (t & 7) * 4;        // 0,4,...,28
        float acc[4] = {0.f, 0.f, 0.f, 0.f};
        for (int qt = 0; qt < 16; ++qt) {
            #pragma unroll
            for (int i = 0; i < 4; ++i) {
                const int idx = t + i * 256;
                const int rr = idx >> 5, cc = idx & 31;
                Av[rr * 33 + cc] =
                    qkv_w[(size_t)(kt * 32 + rr) * 1536 + 1024 + qt * 32 + cc];
                Bo[rr * 33 + cc] =
                    out_w[(size_t)(qt * 32 + rr) * 512 + jt * 32 + cc];
            }
            __syncthreads();
            #pragma unroll 8
            for (int q = 0; q < 32; ++q) {
                const float a = Av[r * 33 + q];
                acc[0] = fmaf(a, Bo[q * 33 + c4 + 0], acc[0]);
                acc[1] = fmaf(a, Bo[q * 33 + c4 + 1], acc[1]);
                acc[2] = fmaf(a, Bo[q * 33 + c4 + 2], acc[2]);
                acc[3] = fmaf(a, Bo[q * 33 + c4 + 3], acc[3]);
            }
            __syncthreads();
        }
        #pragma unroll
        for (int i = 0; i < 4; ++i)
            Weff[(size_t)(kt * 32 + r) * 512 + jt * 32 + c4 + i] = acc[i];
    } else if (bid < NW1 + NW2 + NWE + NBE) {
        // ---- beff[j] = out_b[j] + sum_k qkv_b[1024+k] * Wout[k][j] ----
        const int j = (bid - (NW1 + NW2 + NWE)) * 256 + t;
        smem[t]       = qkv_b[1024 + t];
        smem[256 + t] = qkv_b[1280 + t];
        __syncthreads();
        float acc = out_b[j];
        #pragma unroll 8
        for (int k = 0; k < 512; ++k)
            acc = fmaf(smem[k], out_w[(size_t)k * 512 + j], acc);
        beff[j] = acc;
    } else {
        // ---- LN1 + per-batch partial sums (r2-validated, no atomics) ----
        const int lb   = bid - (NW1 + NW2 + NWE + NBE);   // 0..255
        const int lane = t & 63;
        const int w    = t >> 6;           // wave id == batch id
        const int t0   = lb * 8;

        const float4* G4 = (const float4*)ln1g;
        const float4* B4 = (const float4*)ln1b;
        const float4 g0 = G4[lane], g1 = G4[64 + lane];
        const float4 b0 = B4[lane], b1 = B4[64 + lane];

        float4 acc0 = {0, 0, 0, 0}, acc1 = {0, 0, 0, 0};
        for (int i = 0; i < 8; ++i) {
            const int r = (t0 + i) * NB + w;
            const float4* X4 = (const float4*)(x + (size_t)r * H);
            float4 v0 = X4[lane], v1 = X4[64 + lane];
            float s = hsum8(v0, v1);
            float q = hsq8(v0, v1);
            wave_reduce2(s, q);
            const float mean = s * (1.0f / H);
            const float var  = q * (1.0f / H) - mean * mean;
            const float rs   = 1.0f / sqrtf(var + LN_EPS);
            add4(acc0, ln_apply(v0, mean, rs, g0, b0));
            add4(acc1, ln_apply(v1, mean, rs, g1, b1));
        }
        float4* P4 = (float4*)(partials + ((size_t)w * NCHUNK + lb) * H);
        P4[lane]      = acc0;
        P4[64 + lane] = acc1;
    }
}

// ---------------------------------------------------------------------------
// K1 gemv_eff: cvec[b][j] = beff[j] + (1/T) * sum_k mhsum[b][k] * Weff[k][j]
// where mhsum[b][k] = sum_c partials[b][c][k].  128 blocks x 256 thr.
// Block = (b = bid>>5, 16-wide j chunk). Coalesced everywhere.
// ---------------------------------------------------------------------------
__global__ __launch_bounds__(256) void k_gemv_eff(
    const float* __restrict__ partials, const float* __restrict__ Weff,
    const float* __restrict__ beff, float* __restrict__ cvec)
{
    __shared__ float mh[512];
    __shared__ float red[16][17];
    const int t  = threadIdx.x;
    const int b  = blockIdx.x >> 5;
    const int j0 = (blockIdx.x & 31) * 16;

    // reduce partials[b][256][512] -> mh[512] (2 k's per thread, coalesced)
    float s0 = 0.f, s1 = 0.f;
    const float* P = partials + (size_t)b * NCHUNK * H;
    for (int c = 0; c < NCHUNK; ++c) {
        s0 += P[(size_t)c * H + t];
        s1 += P[(size_t)c * H + 256 + t];
    }
    mh[t]       = s0 * (1.0f / T_);
    mh[256 + t] = s1 * (1.0f / T_);
    __syncthreads();

    const int jj = t & 15, ks = t >> 4;
    const float* wp = Weff + (size_t)(ks * 32) * 512 + j0 + jj;
    float acc = 0.f;
    #pragma unroll 8
    for (int i = 0; i < 32; ++i)
        acc = fmaf(mh[ks * 32 + i], wp[(size_t)i * 512], acc);

    red[ks][jj] = acc;
    __syncthreads();
    if (t < 16) {
        float s = 0.f;
        #pragma unroll
        for (int k2 = 0; k2 < 16; ++k2) s += red[k2][t];
        cvec[(size_t)b * 512 + j0 + t] = s + beff[j0 + t];
    }
}

// ---------------------------------------------------------------------------
// K2: h2 = LN2(x + c[b]) -> bf16 in FRAGMENT ORDER (unchanged, validated)
// ---------------------------------------------------------------------------
__global__ __launch_bounds__(256) void k_ln2(
    const float* __restrict__ x, const float* __restrict__ cvec,
    const float* __restrict__ g, const float* __restrict__ be,
    u16* __restrict__ h2f)
{
    const int lane = threadIdx.x & 63;
    const int w    = threadIdx.x >> 6;
    const int r    = blockIdx.x * 4 + w;
    const int b    = r & 3;

    const float4* X4 = (const float4*)(x + (size_t)r * H);
    const float4* C4 = (const float4*)(cvec + (size_t)b * H);
    float4 v0 = X4[lane * 2],     v1 = X4[lane * 2 + 1];
    add4(v0, C4[lane * 2]);
    add4(v1, C4[lane * 2 + 1]);

    float s = hsum8(v0, v1);
    float q = hsq8(v0, v1);
    wave_reduce2(s, q);
    const float mean = s * (1.0f / H);
    const float var  = q * (1.0f / H) - mean * mean;
    const float rs   = 1.0f / sqrtf(var + LN_EPS);

    const float4* G4 = (const float4*)g;
    const float4* B4 = (const float4*)be;
    float4 h0 = ln_apply(v0, mean, rs, G4[lane * 2],     B4[lane * 2]);
    float4 h1 = ln_apply(v1, mean, rs, G4[lane * 2 + 1], B4[lane * 2 + 1]);

    short8 o;
    o[0] = f2bf(h0.x); o[1] = f2bf(h0.y); o[2] = f2bf(h0.z); o[3] = f2bf(h0.w);
    o[4] = f2bf(h1.x); o[5] = f2bf(h1.y); o[6] = f2bf(h1.z); o[7] = f2bf(h1.w);

    // dest: rt=r>>4, kt=lane>>2, c=(lane&3)*16 + (r&15), kin 0..7
    const size_t idx = (((size_t)(r >> 4) * 16 + (lane >> 2)) << 9)
                     + ((lane & 3) * 16 + (r & 15)) * 8;
    *(short8*)&h2f[idx] = o;
}

// ---------------------------------------------------------------------------
// bf16 MFMA GEMM on fragment-ordered operands (unchanged, validated).
// MODE 0: out -> fragment-ordered bf16 (outfrag), with relu(.+bias)
// MODE 1: out -> row-major fp32 (outf) = .+bias+resid_x+resid_c[row&3], N=512
// ---------------------------------------------------------------------------
template<int MODE>
__global__ __launch_bounds__(256) void gemm_bf16(
    const u16* __restrict__ Af, const u16* __restrict__ Bf,
    const float* __restrict__ bias,
    const float* __restrict__ resid_x, const float* __restrict__ resid_c,
    float* __restrict__ outf, u16* __restrict__ outfrag,
    const int K, const int N)
{
    constexpr int BM = 128, BN = 128, BK = 64;
    const int KT = K >> 5;                 // global k-tiles
    __shared__ alignas(16) u16 As[BM * BK];   // [mt 0..7][ktl 0..1][512]
    __shared__ alignas(16) u16 Bs[BN * BK];

    const int t    = threadIdx.x;
    const int lane = t & 63, w = t >> 6;
    const int wr = w >> 1, wc = w & 1;
    const int lr = lane & 15, lk = lane >> 4;
    const int bmt = blockIdx.x * 8;        // block's first m-tile
    const int bnt = blockIdx.y * 8;        // block's first n-tile

    f32x4 acc[4][4];
    #pragma unroll
    for (int i = 0; i < 4; ++i)
        #pragma unroll
        for (int j = 0; j < 4; ++j)
            acc[i][j] = (f32x4){0.f, 0.f, 0.f, 0.f};

    for (int kt0 = 0; kt0 < KT; kt0 += 2) {
        __syncthreads();
        #pragma unroll
        for (int ft = 0; ft < 4; ++ft) {
            const int f = ft * 256 + t;
            const int mt = f >> 7, ktl = (f >> 6) & 1, c = f & 63;
            gload16(Af + (((size_t)(bmt + mt) * KT + kt0 + ktl) << 9) + c * 8,
                    &As[f * 8]);
        }
        #pragma unroll
        for (int ft = 0; ft < 4; ++ft) {
            const int f = ft * 256 + t;
            const int nt = f >> 7, ktl = (f >> 6) & 1, c = f & 63;
            gload16(Bf + (((size_t)(bnt + nt) * KT + kt0 + ktl) << 9) + c * 8,
                    &Bs[f * 8]);
        }
        __syncthreads();

        #pragma unroll
        for (int ktl = 0; ktl < 2; ++ktl) {
            short8 a[4], b[4];
            #pragma unroll
            for (int i = 0; i < 4; ++i)
                a[i] = *(const short8*)&As[(((wr * 4 + i) * 2 + ktl) << 9) + lane * 8];
            #pragma unroll
            for (int j = 0; j < 4; ++j)
                b[j] = *(const short8*)&Bs[(((wc * 4 + j) * 2 + ktl) << 9) + lane * 8];
            #pragma unroll
            for (int i = 0; i < 4; ++i)
                #pragma unroll
                for (int j = 0; j < 4; ++j)
                    acc[i][j] = __builtin_amdgcn_mfma_f32_16x16x32_bf16(
                        a[i], b[j], acc[i][j], 0, 0, 0);
        }
    }

    // epilogue: D col = lane&15, row = (lane>>4)*4 + reg   [m89/m91]
    const int K2T = N >> 5;   // out-as-A' k-tiles (MODE 0)
    #pragma unroll
    for (int i = 0; i < 4; ++i) {
        const int rt   = bmt + wr * 4 + i;
        const int row0 = rt * 16 + lk * 4;
        #pragma unroll
        for (int j = 0; j < 4; ++j) {
            const int col = (bnt + wc * 4 + j) * 16 + lr;
            const float bv = bias[col];
            #pragma unroll
            for (int r = 0; r < 4; ++r) {
                const int row = row0 + r;
                float v = acc[i][j][r] + bv;
                if (MODE == 0) {
                    v = fmaxf(v, 0.f);
                    const size_t idx =
                        (((size_t)rt * K2T + (col >> 5)) << 9)
                        + (((col >> 3) & 3) * 16 + (lk * 4 + r)) * 8
                        + (col & 7);
                    outfrag[idx] = f2bf(v);
                } else {
                    v += resid_x[(size_t)row * N + col]
                       + resid_c[(row & 3) * N + col];
                    outf[(size_t)row * N + col] = v;
                }
            }
        }
    }
}

// ---------------------------------------------------------------------------
extern "C" void kernel_launch(void* const* d_in, const int* in_sizes, int n_in,
                              void* d_out, int out_size, void* d_ws, size_t ws_size,
                              hipStream_t stream)
{
    const float* x     = (const float*)d_in[0];
    const float* qkv_w = (const float*)d_in[1];
    const float* qkv_b = (const float*)d_in[2];
    const float* out_w = (const float*)d_in[3];
    const float* out_b = (const float*)d_in[4];
    const float* ln1_g = (const float*)d_in[5];
    const float* ln1_b = (const float*)d_in[6];
    const float* ff1_w = (const float*)d_in[7];
    const float* ff1_b = (const float*)d_in[8];
    const float* ff2_w = (const float*)d_in[9];
    const float* ff2_b = (const float*)d_in[10];
    const float* ln2_g = (const float*)d_in[11];
    const float* ln2_b = (const float*)d_in[12];

    float* out = (float*)d_out;

    float* fws      = (float*)d_ws;
    float* partials = fws;                                   // 4*256*512
    float* Weff     = partials + (size_t)NB * NCHUNK * H;    // 512*512
    float* beff     = Weff + (size_t)H * H;                  // 512
    float* cvec     = beff + H;                              // 2048
    u16*   h2f      = (u16*)(cvec + NB * H);                 // M*H    (frag)
    u16*   f1f      = h2f + (size_t)M * H;                   // M*FF   (frag)
    u16*   w1f      = f1f + (size_t)M * FF;                  // FF x H (frag)
    u16*   w2f      = w1f + (size_t)H * FF;                  // H x FF (frag)

    // K0: weight transposes + Weff/beff + LN1 partials (all independent)
    k_mega<<<MEGA_BLOCKS, 256, 0, stream>>>(
        ff1_w, ff2_w, qkv_w, qkv_b, out_w, out_b, x, ln1_g, ln1_b,
        w1f, w2f, Weff, beff, partials);

    // K1: cvec = (reduce partials)/T @ Weff + beff
    k_gemv_eff<<<128, 256, 0, stream>>>(partials, Weff, beff, cvec);

    // K2: h2' = LN2(x + c) in fragment order
    k_ln2<<<M / 4, 256, 0, stream>>>(x, cvec, ln2_g, ln2_b, h2f);

    // K3: f1' = frag(bf16(relu(h2' @ ff1_w + b1)))   [8192,512]@[512,1024]
    gemm_bf16<0><<<dim3(M / 128, FF / 128), 256, 0, stream>>>(
        h2f, w1f, ff1_b, nullptr, nullptr, nullptr, f1f, H, FF);

    // K4: out = x + c + f1' @ ff2_w + b2             [8192,1024]@[1024,512]
    gemm_bf16<1><<<dim3(M / 128, H / 128), 256, 0, stream>>>(
        f1f, w2f, ff2_b, x, cvec, out, nullptr, FF, H);
}